// Round 3
// baseline (295.370 us; speedup 1.0000x reference)
//
#include <hip/hip_runtime.h>

#define Bn 32
#define Tn 24
#define Dn 32
#define Hn 32
#define Cn 1024
#define DC (Dn*Cn)      /* 32768 */
#define TDC (Tn*Dn*Cn)  /* 786432 */

typedef __attribute__((ext_vector_type(8))) short bf16x8;
typedef __attribute__((ext_vector_type(4))) float f32x4;

__device__ __forceinline__ unsigned short f2bf(float f) {
    unsigned u = __builtin_bit_cast(unsigned, f);
    u += 0x7fffu + ((u >> 16) & 1u);
    return (unsigned short)(u >> 16);
}
__device__ __forceinline__ float bf2f(unsigned short h) {
    unsigned u = ((unsigned)h) << 16;
    return __builtin_bit_cast(float, u);
}
__device__ __forceinline__ void splitbf(float f, unsigned short& hi, unsigned short& lo) {
    hi = f2bf(f);
    lo = f2bf(f - bf2f(hi));
}
__device__ __forceinline__ float sigm(float x) {
    return __builtin_amdgcn_rcpf(1.f + __builtin_amdgcn_exp2f(-1.442695041f * x));
}
__device__ __forceinline__ float tanh_(float x) {
    return 1.f - 2.f * __builtin_amdgcn_rcpf(1.f + __builtin_amdgcn_exp2f(2.885390082f * x));
}

struct __align__(16) LdsT {
    unsigned short Xh[4][32][48];     // x hi plane, bf16, padded stride 48
    unsigned short Xl[4][32][48];     // x lo (residual) plane
    unsigned short Hh[2][4][32][48];  // h hi, double-buffered
    unsigned short Hl[2][4][32][48];  // h lo
};

// grid 256 x 512. Block owns 4 consecutive cells; wave w: cell ci=w>>1, hid-half=w&1.
__global__ __launch_bounds__(512, 2)
void lstm_k3(const float* __restrict__ x,
             const float* __restrict__ Wih,
             const float* __restrict__ Whh,
             const float* __restrict__ bih,
             const float* __restrict__ bhh,
             float* __restrict__ sp)  // fp32 out, layout (B,T,C,H)
{
    __shared__ LdsT lds;
    const int tid  = threadIdx.x;
    const int lane = tid & 63;
    const int wave = tid >> 6;
    const int ci   = wave >> 1;
    const int half = wave & 1;
    const int l16  = lane & 15;
    const int kg   = lane >> 4;
    const int bid  = blockIdx.x;
    const int cellbase = (bid & 7) * 128 + (bid >> 3) * 4;  // XCD-contiguous cells
    const int cell = cellbase + ci;

    // ---- load W fragments split hi/lo (B-layout: col=l16 -> gate g, k=kg*8+j) ----
    bf16x8 wihh[4], wihl[4], whhh[4], whhl[4];
    float biasr[4];
#pragma unroll
    for (int q = 0; q < 4; ++q) {
        int g = q * 32 + half * 16 + l16;
        const float* wp = Wih + (size_t)cell * 4096 + g * 32 + kg * 8;
        const float* hp = Whh + (size_t)cell * 4096 + g * 32 + kg * 8;
        union { unsigned short s[8]; bf16x8 v; } a, b, c, d;
#pragma unroll
        for (int j = 0; j < 8; ++j) {
            splitbf(wp[j], a.s[j], b.s[j]);
            splitbf(hp[j], c.s[j], d.s[j]);
        }
        wihh[q] = a.v; wihl[q] = b.v; whhh[q] = c.v; whhl[q] = d.v;
        biasr[q] = bih[cell * 128 + g] + bhh[cell * 128 + g];
    }

    // ---- staging map: thread -> (b, d, d+1) for all 4 cells ----
    const int sb = tid >> 4;          // batch row 0..31
    const int sd = (tid * 2) & 31;    // even d
    const float* xg0 = x + (size_t)sb * TDC + (size_t)sd * Cn + cellbase;

    bf16x8 hfh[2], hfl[2];
    hfh[0] = bf16x8{0,0,0,0,0,0,0,0};
    hfh[1] = hfh[0]; hfl[0] = hfh[0]; hfl[1] = hfh[0];
    float cst[2][4] = {};

    float4 v0 = *(const float4*)xg0;
    float4 v1 = *(const float4*)(xg0 + Cn);

    for (int t = 0; t < Tn; ++t) {
        // stage x(t) -> LDS split hi/lo
        {
            float a0[4] = {v0.x, v0.y, v0.z, v0.w};
            float a1[4] = {v1.x, v1.y, v1.z, v1.w};
#pragma unroll
            for (int cc = 0; cc < 4; ++cc) {
                unsigned short h0, l0, h1, l1;
                splitbf(a0[cc], h0, l0);
                splitbf(a1[cc], h1, l1);
                lds.Xh[cc][sb][sd]     = h0; lds.Xl[cc][sb][sd]     = l0;
                lds.Xh[cc][sb][sd + 1] = h1; lds.Xl[cc][sb][sd + 1] = l1;
            }
        }
        if (t + 1 < Tn) {
            const float* xg = xg0 + (size_t)(t + 1) * DC;
            v0 = *(const float4*)xg;
            v1 = *(const float4*)(xg + Cn);
        }
        __syncthreads();

        // A-fragments of X: row b = mt*16+l16, k = kg*8..kg*8+7
        bf16x8 xfh[2], xfl[2];
#pragma unroll
        for (int mt = 0; mt < 2; ++mt) {
            xfh[mt] = *(const bf16x8*)&lds.Xh[ci][mt * 16 + l16][kg * 8];
            xfl[mt] = *(const bf16x8*)&lds.Xl[ci][mt * 16 + l16][kg * 8];
        }

        f32x4 acc[2][4];
#pragma unroll
        for (int mt = 0; mt < 2; ++mt)
#pragma unroll
            for (int q = 0; q < 4; ++q) {
                f32x4 a = {biasr[q], biasr[q], biasr[q], biasr[q]};
                a = __builtin_amdgcn_mfma_f32_16x16x32_bf16(xfh[mt], wihh[q], a, 0, 0, 0);
                a = __builtin_amdgcn_mfma_f32_16x16x32_bf16(xfl[mt], wihh[q], a, 0, 0, 0);
                a = __builtin_amdgcn_mfma_f32_16x16x32_bf16(xfh[mt], wihl[q], a, 0, 0, 0);
                a = __builtin_amdgcn_mfma_f32_16x16x32_bf16(hfh[mt], whhh[q], a, 0, 0, 0);
                a = __builtin_amdgcn_mfma_f32_16x16x32_bf16(hfl[mt], whhh[q], a, 0, 0, 0);
                a = __builtin_amdgcn_mfma_f32_16x16x32_bf16(hfh[mt], whhl[q], a, 0, 0, 0);
                acc[mt][q] = a;
            }

        // gate update (fp32), write h split hi/lo to Hbuf[t&1]
#pragma unroll
        for (int mt = 0; mt < 2; ++mt)
#pragma unroll
            for (int r = 0; r < 4; ++r) {
                float ig = sigm(acc[mt][0][r]);
                float fg = sigm(acc[mt][1][r]);
                float gg = tanh_(acc[mt][2][r]);
                float og = sigm(acc[mt][3][r]);
                float c  = fg * cst[mt][r] + ig * gg;
                cst[mt][r] = c;
                float h = og * tanh_(c);
                int b = mt * 16 + kg * 4 + r;               // C/D layout: row=(lane>>4)*4+reg
                unsigned short hh, hl;
                splitbf(h, hh, hl);
                lds.Hh[t & 1][ci][b][half * 16 + l16] = hh;
                lds.Hl[t & 1][ci][b][half * 16 + l16] = hl;
            }
        __syncthreads();

        // read h back in A-layout (transpose via LDS) + store fp32 h_t to global
#pragma unroll
        for (int mt = 0; mt < 2; ++mt) {
            hfh[mt] = *(const bf16x8*)&lds.Hh[t & 1][ci][mt * 16 + l16][kg * 8];
            hfl[mt] = *(const bf16x8*)&lds.Hl[t & 1][ci][mt * 16 + l16][kg * 8];
        }
        {
            int b = half * 16 + l16;
            size_t off = (((size_t)b * Tn + t) * Cn + cell) * Hn + kg * 8;
            union { unsigned short s[8]; bf16x8 v; } uh, ul;
            uh.v = hfh[half]; ul.v = hfl[half];
            float4 o0, o1;
            o0.x = bf2f(uh.s[0]) + bf2f(ul.s[0]);
            o0.y = bf2f(uh.s[1]) + bf2f(ul.s[1]);
            o0.z = bf2f(uh.s[2]) + bf2f(ul.s[2]);
            o0.w = bf2f(uh.s[3]) + bf2f(ul.s[3]);
            o1.x = bf2f(uh.s[4]) + bf2f(ul.s[4]);
            o1.y = bf2f(uh.s[5]) + bf2f(ul.s[5]);
            o1.z = bf2f(uh.s[6]) + bf2f(ul.s[6]);
            o1.w = bf2f(uh.s[7]) + bf2f(ul.s[7]);
            *(float4*)(sp + off)     = o0;
            *(float4*)(sp + off + 4) = o1;
        }
    }
}

// grid (B*T) x 256; thread -> pixels (m, n0..n0+3), m=tid>>3, n0=(tid&7)*4.
__global__ __launch_bounds__(256)
void conv_k3(const float* __restrict__ sp,
             const float* __restrict__ cw,
             const float* __restrict__ cb,
             float* __restrict__ out)
{
    __shared__ float4 ldsI[8][32][33];   // [hid4][m][n] padded: 132 KB
    __shared__ float wfS[9][32];
    __shared__ float cbs;
    const int tid = threadIdx.x;
    const float4* sp4 = (const float4*)(sp + (size_t)blockIdx.x * (Cn * Hn));
#pragma unroll
    for (int k = 0; k < 32; ++k) {
        int hc = k & 7;
        int cell = (k >> 3) * 256 + tid;
        float4 f = sp4[cell * 8 + hc];
        ldsI[hc][cell >> 5][cell & 31] = f;
    }
    for (int i = tid; i < 288; i += 256) {
        int tap = i / 32, hid = i % 32;
        wfS[tap][hid] = cw[hid * 9 + tap];
    }
    if (tid == 0) cbs = cb[0];
    __syncthreads();

    const int m  = tid >> 3;
    const int n0 = (tid & 7) * 4;
    float acc[4] = {cbs, cbs, cbs, cbs};

#pragma unroll
    for (int hc = 0; hc < 8; ++hc) {
        float4 w4[9];
#pragma unroll
        for (int tap = 0; tap < 9; ++tap)
            w4[tap] = *(const float4*)&wfS[tap][hc * 4];
#pragma unroll
        for (int dr = 0; dr < 3; ++dr) {
            int mm = m + dr - 1;
            bool rok = (unsigned)mm < 32u;
#pragma unroll
            for (int cc = 0; cc < 6; ++cc) {
                int nn = n0 + cc - 1;
                float4 v = {0.f, 0.f, 0.f, 0.f};
                if (rok && (unsigned)nn < 32u) v = ldsI[hc][mm][nn];
#pragma unroll
                for (int j = 0; j < 4; ++j) {
                    if (j < cc - 2 || j > cc) continue;   // tap col offset in [-1,1]
                    float4 w = w4[dr * 3 + (cc - j)];
                    acc[j] = fmaf(v.x, w.x, acc[j]);
                    acc[j] = fmaf(v.y, w.y, acc[j]);
                    acc[j] = fmaf(v.z, w.z, acc[j]);
                    acc[j] = fmaf(v.w, w.w, acc[j]);
                }
            }
        }
    }
    float4 o;
    o.x = sigm(acc[0]); o.y = sigm(acc[1]); o.z = sigm(acc[2]); o.w = sigm(acc[3]);
    *(float4*)&out[(size_t)blockIdx.x * 1024 + m * 32 + n0] = o;
}

extern "C" void kernel_launch(void* const* d_in, const int* in_sizes, int n_in,
                              void* d_out, int out_size, void* d_ws, size_t ws_size,
                              hipStream_t stream) {
    const float* x   = (const float*)d_in[0];
    const float* Wih = (const float*)d_in[1];
    const float* Whh = (const float*)d_in[2];
    const float* bih = (const float*)d_in[3];
    const float* bhh = (const float*)d_in[4];
    const float* cw  = (const float*)d_in[5];
    const float* cb  = (const float*)d_in[6];
    float* out = (float*)d_out;
    float* sp = (float*)d_ws;  // fp32 spatial (B,T,C,H), 100.7 MB

    lstm_k3<<<256, 512, 0, stream>>>(x, Wih, Whh, bih, bhh, sp);
    conv_k3<<<Bn * Tn, 256, 0, stream>>>(sp, cw, cb, out);
}

// Round 4
// 102.407 us; speedup vs baseline: 2.8843x; 2.8843x over previous
//
#include <hip/hip_runtime.h>

#define Bn 32
#define Tn 24
#define Dn 32
#define Hn 32
#define Cn 1024
#define DC (Dn*Cn)      /* 32768 */
#define TDC (Tn*Dn*Cn)  /* 786432 */
#define MP 34
#define PPXN (MP*MP)    /* 1156 */
#define IMGS (MP*MP*32) /* shorts per image: 4 planes * 1156 * 8 = 36992 */
#define SCALE 1.442695041f

typedef __attribute__((ext_vector_type(8))) short bf16x8;
typedef __attribute__((ext_vector_type(4))) float f32x4;

union U8 { unsigned u[4]; int4 i; bf16x8 v; };

__device__ __forceinline__ unsigned cvt_pk(float lo, float hi) {
    unsigned r; asm("v_cvt_pk_bf16_f32 %0, %1, %2" : "=v"(r) : "v"(lo), "v"(hi)); return r;
}
__device__ __forceinline__ float lo16f(unsigned u) { return __builtin_bit_cast(float, u << 16); }
__device__ __forceinline__ float hi16f(unsigned u) { return __builtin_bit_cast(float, u & 0xffff0000u); }
__device__ __forceinline__ float rcp_(float x) { return __builtin_amdgcn_rcpf(x); }
__device__ __forceinline__ float exp2_(float x) { return __builtin_amdgcn_exp2f(x); }

struct __align__(16) LdsL {
    unsigned short Xh[2][2][32][48];  // [buf][cell][b][d pad48] hi plane
    unsigned short Xl[2][2][32][48];  // lo plane
    float Hf[2][2][32][36];           // [buf][cell][b][hid pad36] fp32 h
};

// ---- zero the 1-px halo ring of every (img, chunk) plane: 3072 planes x 132 px ----
__global__ __launch_bounds__(512)
void zero_halo(unsigned short* __restrict__ sp) {
    int gid = blockIdx.x * 512 + threadIdx.x;
    if (gid >= 3072 * 132) return;
    int plane = gid / 132;
    int r = gid - plane * 132;
    int m, n;
    if (r < 34)       { m = 0;      n = r; }
    else if (r < 68)  { m = 33;     n = r - 34; }
    else if (r < 100) { m = r - 67; n = 0; }
    else              { m = r - 99; n = 33; }
    int4 z = {0, 0, 0, 0};
    *(int4*)(sp + ((size_t)plane * PPXN + m * MP + n) * 8) = z;
}

// ---- LSTM: 512 blocks x 256 thr; block owns 2 cells; wave w: ci=w>>1, half=w&1 ----
__global__ __launch_bounds__(256, 3)
void lstm_k4(const float* __restrict__ x,
             const float* __restrict__ Wih,
             const float* __restrict__ Whh,
             const float* __restrict__ bih,
             const float* __restrict__ bhh,
             unsigned short* __restrict__ sp)
{
    __shared__ LdsL lds;
    const int tid  = threadIdx.x;
    const int lane = tid & 63;
    const int wave = tid >> 6;
    const int ci   = wave >> 1;
    const int half = wave & 1;
    const int l16  = lane & 15;
    const int kg   = lane >> 4;
    const int bid  = blockIdx.x;
    const int cellbase = (bid & 7) * 128 + (bid >> 3) * 2;  // XCD-contiguous cells
    const int cell = cellbase + ci;

    // ---- W fragments, split hi/lo via cvt_pk (pairs along k), pre-scaled by log2e ----
    U8 wihh[4], wihl[4], whhh[4], whhl[4];
    float biasr[4];
#pragma unroll
    for (int q = 0; q < 4; ++q) {
        const int g = q * 32 + half * 16 + l16;
        const float* wp = Wih + (size_t)cell * 4096 + g * 32 + kg * 8;
        const float* hp = Whh + (size_t)cell * 4096 + g * 32 + kg * 8;
        float wv[8], hv[8];
#pragma unroll
        for (int j = 0; j < 8; ++j) { wv[j] = wp[j] * SCALE; hv[j] = hp[j] * SCALE; }
#pragma unroll
        for (int p = 0; p < 4; ++p) {
            unsigned a = cvt_pk(wv[2*p], wv[2*p+1]);
            wihh[q].u[p] = a;
            wihl[q].u[p] = cvt_pk(wv[2*p] - lo16f(a), wv[2*p+1] - hi16f(a));
            unsigned b = cvt_pk(hv[2*p], hv[2*p+1]);
            whhh[q].u[p] = b;
            whhl[q].u[p] = cvt_pk(hv[2*p] - lo16f(b), hv[2*p+1] - hi16f(b));
        }
        biasr[q] = (bih[cell * 128 + g] + bhh[cell * 128 + g]) * SCALE;
    }

    // ---- staging map: thread -> (b=tid>>3, d0=(tid&7)*4), float2 covers 2 cells ----
    const int sb = tid >> 3;
    const int d0 = (tid & 7) * 4;
    const float* xg0 = x + (size_t)sb * TDC + (size_t)d0 * Cn + cellbase;

    // sp store base for this lane's rows (b = half*16+l16, chunk kg)
    const int sm = cell >> 5, sn = cell & 31;
    const int ppx = (sm + 1) * MP + (sn + 1);
    unsigned short* spb = sp + ((size_t)(half * 16 + l16) * Tn * 4 + kg) * (PPXN * 8)
                             + (size_t)ppx * 8;

    float hD[8] = {};   // h_{t-1} in D-layout (rows mt*16+kg*4+r)
    float cst[8] = {};
    float2 nx[4];
#pragma unroll
    for (int k = 0; k < 4; ++k) nx[k] = *(const float2*)(xg0 + k * Cn);

    for (int t = 0; t < Tn; ++t) {
        const int bufi = t & 1;
        // -- stage x(t): split hi/lo, b64 writes --
#pragma unroll
        for (int cc = 0; cc < 2; ++cc) {
            float f0 = cc ? nx[0].y : nx[0].x;
            float f1 = cc ? nx[1].y : nx[1].x;
            float f2 = cc ? nx[2].y : nx[2].x;
            float f3 = cc ? nx[3].y : nx[3].x;
            unsigned a0 = cvt_pk(f0, f1), a1 = cvt_pk(f2, f3);
            float l0 = f0 - lo16f(a0), l1 = f1 - hi16f(a0);
            float l2 = f2 - lo16f(a1), l3 = f3 - hi16f(a1);
            int2 hi2 = {(int)a0, (int)a1};
            int2 lo2 = {(int)cvt_pk(l0, l1), (int)cvt_pk(l2, l3)};
            *(int2*)&lds.Xh[bufi][cc][sb][d0] = hi2;
            *(int2*)&lds.Xl[bufi][cc][sb][d0] = lo2;
        }
        // -- write h_{t-1} (D-layout regs) to Hf[bufi] --
#pragma unroll
        for (int i = 0; i < 8; ++i) {
            int mt = i >> 2, r = i & 3;
            lds.Hf[bufi][ci][mt * 16 + kg * 4 + r][half * 16 + l16] = hD[i];
        }
        // -- prefetch x(t+1) --
        if (t < Tn - 1) {
#pragma unroll
            for (int k = 0; k < 4; ++k)
                nx[k] = *(const float2*)(xg0 + (size_t)(t + 1) * DC + k * Cn);
        }
        __syncthreads();

        // -- A-fragments of X --
        U8 xfh[2], xfl[2];
#pragma unroll
        for (int mt = 0; mt < 2; ++mt) {
            xfh[mt].v = *(const bf16x8*)&lds.Xh[bufi][ci][mt * 16 + l16][kg * 8];
            xfl[mt].v = *(const bf16x8*)&lds.Xl[bufi][ci][mt * 16 + l16][kg * 8];
        }
        // -- A-fragments of h_{t-1}: fp32 -> hi/lo bf16 pairs (cvt_pk along k) --
        U8 hfh[2], hfl[2];
        unsigned sphi[4];
#pragma unroll
        for (int mt = 0; mt < 2; ++mt) {
            const float* hp = &lds.Hf[bufi][ci][mt * 16 + l16][kg * 8];
            float4 ha = *(const float4*)hp;
            float4 hb = *(const float4*)(hp + 4);
            float e0 = ha.x, e1 = ha.y, e2 = ha.z, e3 = ha.w;
            float e4 = hb.x, e5 = hb.y, e6 = hb.z, e7 = hb.w;
            unsigned p0 = cvt_pk(e0, e1), p1 = cvt_pk(e2, e3);
            unsigned p2 = cvt_pk(e4, e5), p3 = cvt_pk(e6, e7);
            hfh[mt].u[0] = p0; hfh[mt].u[1] = p1; hfh[mt].u[2] = p2; hfh[mt].u[3] = p3;
            hfl[mt].u[0] = cvt_pk(e0 - lo16f(p0), e1 - hi16f(p0));
            hfl[mt].u[1] = cvt_pk(e2 - lo16f(p1), e3 - hi16f(p1));
            hfl[mt].u[2] = cvt_pk(e4 - lo16f(p2), e5 - hi16f(p2));
            hfl[mt].u[3] = cvt_pk(e6 - lo16f(p3), e7 - hi16f(p3));
            if (mt == half) { sphi[0] = p0; sphi[1] = p1; sphi[2] = p2; sphi[3] = p3; }
        }
        // -- store h_{t-1} (bf16 hi) to sp --
        if (t > 0) {
            int4 sv = {(int)sphi[0], (int)sphi[1], (int)sphi[2], (int)sphi[3]};
            *(int4*)(spb + (size_t)(t - 1) * IMGS) = sv;
        }

        // -- MFMA: 3-term split x 2 paths --
        f32x4 acc[2][4];
#pragma unroll
        for (int mt = 0; mt < 2; ++mt)
#pragma unroll
            for (int q = 0; q < 4; ++q) {
                f32x4 a = {biasr[q], biasr[q], biasr[q], biasr[q]};
                a = __builtin_amdgcn_mfma_f32_16x16x32_bf16(xfh[mt].v, wihh[q].v, a, 0, 0, 0);
                a = __builtin_amdgcn_mfma_f32_16x16x32_bf16(xfl[mt].v, wihh[q].v, a, 0, 0, 0);
                a = __builtin_amdgcn_mfma_f32_16x16x32_bf16(xfh[mt].v, wihl[q].v, a, 0, 0, 0);
                a = __builtin_amdgcn_mfma_f32_16x16x32_bf16(hfh[mt].v, whhh[q].v, a, 0, 0, 0);
                a = __builtin_amdgcn_mfma_f32_16x16x32_bf16(hfl[mt].v, whhh[q].v, a, 0, 0, 0);
                a = __builtin_amdgcn_mfma_f32_16x16x32_bf16(hfh[mt].v, whhl[q].v, a, 0, 0, 0);
                acc[mt][q] = a;
            }

        // -- gates (pre-scaled by log2e: exp2 direct) --
#pragma unroll
        for (int mt = 0; mt < 2; ++mt)
#pragma unroll
            for (int r = 0; r < 4; ++r) {
                float gi = acc[mt][0][r], gf = acc[mt][1][r];
                float gg = acc[mt][2][r], go = acc[mt][3][r];
                float ig = rcp_(1.f + exp2_(-gi));
                float fg = rcp_(1.f + exp2_(-gf));
                float gt = 1.f - 2.f * rcp_(1.f + exp2_(gg + gg));
                float og = rcp_(1.f + exp2_(-go));
                float c  = fg * cst[mt * 4 + r] + ig * gt;
                cst[mt * 4 + r] = c;
                float tc = 1.f - 2.f * rcp_(1.f + exp2_((2.f * SCALE) * c));
                hD[mt * 4 + r] = og * tc;
            }
    }

    // ---- epilogue: flush h_23 ----
#pragma unroll
    for (int i = 0; i < 8; ++i) {
        int mt = i >> 2, r = i & 3;
        lds.Hf[0][ci][mt * 16 + kg * 4 + r][half * 16 + l16] = hD[i];
    }
    __syncthreads();
    {
        const float* hp = &lds.Hf[0][ci][half * 16 + l16][kg * 8];
        float4 ha = *(const float4*)hp;
        float4 hb = *(const float4*)(hp + 4);
        int4 sv = {(int)cvt_pk(ha.x, ha.y), (int)cvt_pk(ha.z, ha.w),
                   (int)cvt_pk(hb.x, hb.y), (int)cvt_pk(hb.z, hb.w)};
        *(int4*)(spb + (size_t)(Tn - 1) * IMGS) = sv;
    }
}

// ---- conv: 768 blocks (b,t) x 512 thr, 2 px/thread, fp32 math, fused sigmoid ----
__global__ __launch_bounds__(512, 4)
void conv_k4(const unsigned short* __restrict__ sp,
             const float* __restrict__ cw,
             const float* __restrict__ cb,
             float* __restrict__ out)
{
    __shared__ float wlds[9][32];
    const int tid = threadIdx.x;
    const int img = blockIdx.x;
    if (tid < 288) wlds[tid >> 5][tid & 31] = cw[(tid & 31) * 9 + (tid >> 5)];
    __syncthreads();
    const float bias = cb[0];
    float acc[2] = {bias, bias};
    int ppx[2];
#pragma unroll
    for (int pk = 0; pk < 2; ++pk) {
        int px = tid + pk * 512;
        ppx[pk] = ((px >> 5) + 1) * MP + (px & 31) + 1;
    }
#pragma unroll
    for (int hc = 0; hc < 4; ++hc) {
        float4 wa[9], wb[9];
#pragma unroll
        for (int tap = 0; tap < 9; ++tap) {
            wa[tap] = *(const float4*)&wlds[tap][hc * 8];
            wb[tap] = *(const float4*)&wlds[tap][hc * 8 + 4];
        }
        const unsigned short* plane = sp + (size_t)(img * 4 + hc) * (PPXN * 8);
#pragma unroll
        for (int pk = 0; pk < 2; ++pk) {
            const unsigned short* base = plane + (size_t)ppx[pk] * 8;
            float a = acc[pk];
#pragma unroll
            for (int dm = -1; dm <= 1; ++dm)
#pragma unroll
                for (int dn = -1; dn <= 1; ++dn) {
                    const int tap = (dm + 1) * 3 + (dn + 1);
                    int4 v = *(const int4*)(base + (dm * MP + dn) * 8);
                    float4 w0 = wa[tap], w1 = wb[tap];
                    a = fmaf(lo16f((unsigned)v.x), w0.x, a);
                    a = fmaf(hi16f((unsigned)v.x), w0.y, a);
                    a = fmaf(lo16f((unsigned)v.y), w0.z, a);
                    a = fmaf(hi16f((unsigned)v.y), w0.w, a);
                    a = fmaf(lo16f((unsigned)v.z), w1.x, a);
                    a = fmaf(hi16f((unsigned)v.z), w1.y, a);
                    a = fmaf(lo16f((unsigned)v.w), w1.z, a);
                    a = fmaf(hi16f((unsigned)v.w), w1.w, a);
                }
            acc[pk] = a;
        }
    }
#pragma unroll
    for (int pk = 0; pk < 2; ++pk)
        out[(size_t)img * 1024 + tid + pk * 512] = rcp_(1.f + exp2_(-SCALE * acc[pk]));
}

extern "C" void kernel_launch(void* const* d_in, const int* in_sizes, int n_in,
                              void* d_out, int out_size, void* d_ws, size_t ws_size,
                              hipStream_t stream) {
    const float* x   = (const float*)d_in[0];
    const float* Wih = (const float*)d_in[1];
    const float* Whh = (const float*)d_in[2];
    const float* bih = (const float*)d_in[3];
    const float* bhh = (const float*)d_in[4];
    const float* cw  = (const float*)d_in[5];
    const float* cb  = (const float*)d_in[6];
    float* out = (float*)d_out;
    unsigned short* sp = (unsigned short*)d_ws;  // bf16 (B,T, chunk4, 34,34, 8ch), 56.8 MB

    zero_halo<<<792, 512, 0, stream>>>(sp);
    lstm_k4<<<512, 256, 0, stream>>>(x, Wih, Whh, bih, bhh, sp);
    conv_k4<<<Bn * Tn, 512, 0, stream>>>(sp, cw, cb, out);
}